// Round 1
// baseline (424.552 us; speedup 1.0000x reference)
//
#include <hip/hip_runtime.h>
#include <hip/hip_bf16.h>
#include <stdint.h>

// ---------- types ----------
typedef unsigned short u16;
typedef __bf16 bf16x8 __attribute__((ext_vector_type(8)));
typedef u16   u16x8  __attribute__((ext_vector_type(8)));
typedef u16   u16x4  __attribute__((ext_vector_type(4)));
typedef float f32x4  __attribute__((ext_vector_type(4)));

__device__ __forceinline__ u16 f2bf(float f) {
  union { float f; uint32_t u; } v; v.f = f;
  uint32_t r = v.u + 0x7fffu + ((v.u >> 16) & 1u);   // RNE
  return (u16)(r >> 16);
}

// async global->LDS, 16B per lane; LDS dest must be wave-uniform base (+lane*16 by HW)
typedef __attribute__((address_space(1))) void gvoid_t;
typedef __attribute__((address_space(3))) void lvoid_t;
__device__ __forceinline__ void gload_lds16(const void* g, void* l) {
  __builtin_amdgcn_global_load_lds((gvoid_t*)g, (lvoid_t*)l, 16, 0, 0);
}

// ---------- LayerNorm (f32 in -> bf16 out), 1024 cols, one row per block ----------
__global__ __launch_bounds__(256)
void ln_kernel(const float* __restrict__ x, const float* __restrict__ g,
               const float* __restrict__ b, u16* __restrict__ out) {
  const int row = blockIdx.x;
  const int tid = threadIdx.x;
  const float* xr = x + (size_t)row * 1024;
  f32x4 v = *(const f32x4*)&xr[tid * 4];
  float s = v[0] + v[1] + v[2] + v[3];
  float q = v[0]*v[0] + v[1]*v[1] + v[2]*v[2] + v[3]*v[3];
  #pragma unroll
  for (int o = 32; o > 0; o >>= 1) { s += __shfl_xor(s, o); q += __shfl_xor(q, o); }
  __shared__ float ss[4], qq[4];
  if ((tid & 63) == 0) { ss[tid >> 6] = s; qq[tid >> 6] = q; }
  __syncthreads();
  s = ss[0] + ss[1] + ss[2] + ss[3];
  q = qq[0] + qq[1] + qq[2] + qq[3];
  float mu = s * (1.0f / 1024.0f);
  float var = q * (1.0f / 1024.0f) - mu * mu;
  float rstd = rsqrtf(var + 1e-5f);
  u16x4 o4;
  #pragma unroll
  for (int i = 0; i < 4; ++i)
    o4[i] = f2bf((v[i] - mu) * rstd * g[tid * 4 + i] + b[tid * 4 + i]);
  *(u16x4*)&out[(size_t)row * 1024 + tid * 4] = o4;
}

// ---------- transpose + cast: W f32 [K][N] -> Wt bf16 [N][K] ----------
__global__ __launch_bounds__(256)
void transpose_cast(const float* __restrict__ W, u16* __restrict__ Wt, int K, int N) {
  __shared__ float t[32][33];
  const int n0 = blockIdx.x * 32, k0 = blockIdx.y * 32;
  const int tx = threadIdx.x & 31, ty = threadIdx.x >> 5;  // ty 0..7
  #pragma unroll
  for (int i = 0; i < 4; ++i)
    t[ty + 8*i][tx] = W[(size_t)(k0 + ty + 8*i) * N + n0 + tx];
  __syncthreads();
  #pragma unroll
  for (int i = 0; i < 4; ++i)
    Wt[(size_t)(n0 + ty + 8*i) * K + k0 + tx] = f2bf(t[tx][ty + 8*i]);
}

// ---------- GEMM: C[M][N] = A[M][K] @ Bt[N][K]^T  (both bf16, f32 accum) ----------
// EPI: 0 = store bf16; 1 = +bias, exact GELU, store bf16; 2 = +bias +resid, store f32
template<int EPI>
__global__ __launch_bounds__(256, 2)
void gemm_bt(const u16* __restrict__ A, const u16* __restrict__ Bt,
             void* __restrict__ out, const float* __restrict__ bias,
             const float* __restrict__ resid, int M, int N, int K) {
  __shared__ u16 As[128 * 32];
  __shared__ u16 Bs[128 * 32];
  const int tid = threadIdx.x;
  const int w = tid >> 6, l = tid & 63;
  const int bm = blockIdx.x * 128, bn = blockIdx.y * 128;
  const int wr = (w >> 1) * 64, wc = (w & 1) * 64;
  const int l15 = l & 15, lhi = l >> 4;
  f32x4 acc[4][4] = {};

  const int r4 = tid >> 2;          // 0..63
  const int c8 = (tid & 3) * 8;     // elem offset within 32-elem K slab
  const u16* ga0 = A  + (size_t)(bm + r4) * K + c8;
  const u16* ga1 = ga0 + (size_t)64 * K;
  const u16* gb0 = Bt + (size_t)(bn + r4) * K + c8;
  const u16* gb1 = gb0 + (size_t)64 * K;
  u16* lA0 = &As[(w * 16) * 32];
  u16* lA1 = &As[(64 + w * 16) * 32];
  u16* lB0 = &Bs[(w * 16) * 32];
  u16* lB1 = &Bs[(64 + w * 16) * 32];

  const int arow = (wr + l15) * 32 + lhi * 8;
  const int brow = (wc + l15) * 32 + lhi * 8;

  for (int k0 = 0; k0 < K; k0 += 32) {
    gload_lds16(ga0 + k0, lA0);
    gload_lds16(ga1 + k0, lA1);
    gload_lds16(gb0 + k0, lB0);
    gload_lds16(gb1 + k0, lB1);
    __syncthreads();               // drains vmcnt(0): tiles resident
    bf16x8 a[4], b[4];
    #pragma unroll
    for (int m = 0; m < 4; ++m) a[m] = *(const bf16x8*)&As[arow + m * 16 * 32];
    #pragma unroll
    for (int n = 0; n < 4; ++n) b[n] = *(const bf16x8*)&Bs[brow + n * 16 * 32];
    #pragma unroll
    for (int m = 0; m < 4; ++m)
      #pragma unroll
      for (int n = 0; n < 4; ++n)
        acc[m][n] = __builtin_amdgcn_mfma_f32_16x16x32_bf16(a[m], b[n], acc[m][n], 0, 0, 0);
    __syncthreads();               // all waves done reading before restage
  }

  // epilogue: C/D frag -> row=(l>>4)*4+r, col=l&15
  #pragma unroll
  for (int m = 0; m < 4; ++m) {
    #pragma unroll
    for (int n = 0; n < 4; ++n) {
      #pragma unroll
      for (int r = 0; r < 4; ++r) {
        const int grow = bm + wr + m * 16 + lhi * 4 + r;
        const int gcol = bn + wc + n * 16 + l15;
        float vv = acc[m][n][r];
        if constexpr (EPI >= 1) vv += bias[gcol];
        if constexpr (EPI == 1) vv = 0.5f * vv * (1.0f + erff(vv * 0.70710678118f));
        if constexpr (EPI == 2) {
          vv += resid[(size_t)grow * N + gcol];
          ((float*)out)[(size_t)grow * N + gcol] = vv;
        } else {
          ((u16*)out)[(size_t)grow * N + gcol] = f2bf(vv);
        }
      }
    }
  }
}

// ---------- fused flash attention ----------
// qkv: bf16 [B*S][3072] (q|k|v each 1024 = 16 heads * 64)
// bias: f32 [H][S][S]; ctx out: bf16 [B*S][1024]
__global__ __launch_bounds__(256, 2)
void attn_kernel(const u16* __restrict__ qkv, const float* __restrict__ bias,
                 u16* __restrict__ ctx) {
  const int qt = blockIdx.x;          // 0..31  (q tile of 64 rows)
  const int bh = blockIdx.y;          // 0..31
  const int b = bh >> 4, h = bh & 15;
  const int tid = threadIdx.x, w = tid >> 6, l = tid & 63;
  const int l15 = l & 15, lhi = l >> 4;
  const size_t ld = 3072;

  __shared__ u16 Kl[64 * 72];         // K tile [key][72] (64 used)
  __shared__ u16 Vt[64 * 72];         // V^T tile [d][72] (64 keys used)
  __shared__ u16 Pl[4][16 * 72];      // per-wave P tile [qrow][72]

  const u16* qp = qkv;
  const u16* kp = qkv + 1024;
  const u16* vp = qkv + 2048;

  // Q fragments (16 q rows per wave), A-frag layout: row=l&15, k=(l>>4)*8+i
  bf16x8 qf[2];
  {
    const u16* qrow = qp + (size_t)(b * 2048 + qt * 64 + w * 16 + l15) * ld + h * 64 + lhi * 8;
    qf[0] = *(const bf16x8*)qrow;
    qf[1] = *(const bf16x8*)(qrow + 32);
  }

  float m_run[4] = {-1e30f, -1e30f, -1e30f, -1e30f};
  float s_run[4] = {0.f, 0.f, 0.f, 0.f};
  f32x4 octx[4] = {};                 // ctx accum, 4 d-frags of 16

  const int key = tid & 63, dh = (tid >> 6) * 16;
  const u16* kgl = kp + (size_t)(b * 2048 + key) * ld + h * 64 + dh;
  const u16* vgl = vp + (size_t)(b * 2048 + key) * ld + h * 64 + dh;

  for (int kv0 = 0; kv0 < 2048; kv0 += 64) {
    // ---- stage K (row-major, pad 72) and V (transposed) ----
    u16x8 k0v = *(const u16x8*)(kgl + (size_t)kv0 * ld);
    u16x8 k1v = *(const u16x8*)(kgl + (size_t)kv0 * ld + 8);
    u16x8 v0v = *(const u16x8*)(vgl + (size_t)kv0 * ld);
    u16x8 v1v = *(const u16x8*)(vgl + (size_t)kv0 * ld + 8);
    *(u16x8*)&Kl[key * 72 + dh] = k0v;
    *(u16x8*)&Kl[key * 72 + dh + 8] = k1v;
    #pragma unroll
    for (int i = 0; i < 8; ++i) {
      Vt[(dh + i) * 72 + key]     = v0v[i];
      Vt[(dh + 8 + i) * 72 + key] = v1v[i];
    }
    __syncthreads();

    // ---- S = Q @ K^T : 4 key-frags x 2 k-slices ----
    f32x4 sa[4] = {};
    #pragma unroll
    for (int nf = 0; nf < 4; ++nf) {
      bf16x8 kf0 = *(const bf16x8*)&Kl[(nf * 16 + l15) * 72 + lhi * 8];
      bf16x8 kf1 = *(const bf16x8*)&Kl[(nf * 16 + l15) * 72 + 32 + lhi * 8];
      sa[nf] = __builtin_amdgcn_mfma_f32_16x16x32_bf16(qf[0], kf0, sa[nf], 0, 0, 0);
      sa[nf] = __builtin_amdgcn_mfma_f32_16x16x32_bf16(qf[1], kf1, sa[nf], 0, 0, 0);
    }

    // ---- scale + bias + online softmax (rows live in C/D frag regs) ----
    float sval[4][4];                 // [nf][r]
    const size_t brow0 = (size_t)(h * 2048 + qt * 64 + w * 16 + lhi * 4) * 2048 + kv0 + l15;
    #pragma unroll
    for (int r = 0; r < 4; ++r)
      #pragma unroll
      for (int nf = 0; nf < 4; ++nf)
        sval[nf][r] = sa[nf][r] * 0.125f + bias[brow0 + (size_t)r * 2048 + nf * 16];

    #pragma unroll
    for (int r = 0; r < 4; ++r) {
      float mx = fmaxf(fmaxf(sval[0][r], sval[1][r]), fmaxf(sval[2][r], sval[3][r]));
      mx = fmaxf(mx, __shfl_xor(mx, 1));
      mx = fmaxf(mx, __shfl_xor(mx, 2));
      mx = fmaxf(mx, __shfl_xor(mx, 4));
      mx = fmaxf(mx, __shfl_xor(mx, 8));
      const float mnew = fmaxf(m_run[r], mx);
      const float fs = __expf(m_run[r] - mnew);
      s_run[r] *= fs;
      #pragma unroll
      for (int nf = 0; nf < 4; ++nf) octx[nf][r] *= fs;
      float ps = 0.f;
      #pragma unroll
      for (int nf = 0; nf < 4; ++nf) {
        float p = __expf(sval[nf][r] - mnew);
        sval[nf][r] = p;
        ps += p;
      }
      ps += __shfl_xor(ps, 1); ps += __shfl_xor(ps, 2);
      ps += __shfl_xor(ps, 4); ps += __shfl_xor(ps, 8);
      s_run[r] += ps;
      m_run[r] = mnew;
    }

    // ---- P -> LDS (C/D layout scatter), then PV ----
    #pragma unroll
    for (int r = 0; r < 4; ++r)
      #pragma unroll
      for (int nf = 0; nf < 4; ++nf)
        Pl[w][(lhi * 4 + r) * 72 + nf * 16 + l15] = f2bf(sval[nf][r]);
    __syncthreads();                  // lgkmcnt(0): P writes visible before A-frag reads

    #pragma unroll
    for (int ks = 0; ks < 2; ++ks) {
      bf16x8 pa = *(const bf16x8*)&Pl[w][l15 * 72 + ks * 32 + lhi * 8];
      #pragma unroll
      for (int nf = 0; nf < 4; ++nf) {
        bf16x8 bv = *(const bf16x8*)&Vt[(nf * 16 + l15) * 72 + ks * 32 + lhi * 8];
        octx[nf] = __builtin_amdgcn_mfma_f32_16x16x32_bf16(pa, bv, octx[nf], 0, 0, 0);
      }
    }
    __syncthreads();                  // all waves done with Kl/Vt before restage
  }

  // ---- normalize + write ctx ----
  #pragma unroll
  for (int nf = 0; nf < 4; ++nf)
    #pragma unroll
    for (int r = 0; r < 4; ++r) {
      const int grow = b * 2048 + qt * 64 + w * 16 + lhi * 4 + r;
      const int gcol = h * 64 + nf * 16 + l15;
      ctx[(size_t)grow * 1024 + gcol] = f2bf(octx[nf][r] / s_run[r]);
    }
}

// ---------- launch ----------
extern "C" void kernel_launch(void* const* d_in, const int* in_sizes, int n_in,
                              void* d_out, int out_size, void* d_ws, size_t ws_size,
                              hipStream_t stream) {
  const float* x    = (const float*)d_in[0];
  const float* rb   = (const float*)d_in[1];
  const float* wq   = (const float*)d_in[2];
  const float* wk   = (const float*)d_in[3];
  const float* wv   = (const float*)d_in[4];
  const float* wo   = (const float*)d_in[5];
  const float* wo_b = (const float*)d_in[6];
  const float* w1   = (const float*)d_in[7];
  const float* b1   = (const float*)d_in[8];
  const float* w2   = (const float*)d_in[9];
  const float* b2   = (const float*)d_in[10];
  const float* ln1g = (const float*)d_in[11];
  const float* ln1b = (const float*)d_in[12];
  const float* ln2g = (const float*)d_in[13];
  const float* ln2b = (const float*)d_in[14];

  char* ws = (char*)d_ws;
  u16*   xn    = (u16*)(ws + 0);                    //  8 MB  [4096][1024] bf16
  u16*   qkvb  = (u16*)(ws + (8u << 20));           // 24 MB  [4096][3072] bf16
  u16*   hbuf  = (u16*)(ws + (8u << 20));           // 32 MB  [4096][4096] bf16 (reuses qkv+ctx)
  u16*   ctxb  = (u16*)(ws + (32u << 20));          //  8 MB  [4096][1024] bf16
  float* x1    = (float*)(ws + (40u << 20));        // 16 MB  [4096][1024] f32
  u16*   wqkvt = (u16*)(ws + (56u << 20));          //  6 MB  [3072][1024] bf16
  u16*   wot   = (u16*)(ws + (62u << 20));          //  2 MB  [1024][1024] bf16
  u16*   w1t   = (u16*)(ws + (64u << 20));          //  8 MB  [4096][1024] bf16
  u16*   w2t   = (u16*)(ws + (72u << 20));          //  8 MB  [1024][4096] bf16

  // weight transposes (f32 [K][N] -> bf16 [N][K])
  transpose_cast<<<dim3(32, 32),  256, 0, stream>>>(wq, wqkvt,                 1024, 1024);
  transpose_cast<<<dim3(32, 32),  256, 0, stream>>>(wk, wqkvt + 1024 * 1024,   1024, 1024);
  transpose_cast<<<dim3(32, 32),  256, 0, stream>>>(wv, wqkvt + 2048 * 1024,   1024, 1024);
  transpose_cast<<<dim3(32, 32),  256, 0, stream>>>(wo, wot,                   1024, 1024);
  transpose_cast<<<dim3(128, 32), 256, 0, stream>>>(w1, w1t,                   1024, 4096);
  transpose_cast<<<dim3(32, 128), 256, 0, stream>>>(w2, w2t,                   4096, 1024);

  // LN1 -> xn
  ln_kernel<<<4096, 256, 0, stream>>>(x, ln1g, ln1b, xn);
  // fused QKV: [4096][3072]
  gemm_bt<0><<<dim3(32, 24), 256, 0, stream>>>(xn, wqkvt, qkvb, nullptr, nullptr, 4096, 3072, 1024);
  // attention -> ctx
  attn_kernel<<<dim3(32, 32), 256, 0, stream>>>(qkvb, rb, ctxb);
  // O-proj + wo_b + residual x -> x1 (f32)
  gemm_bt<2><<<dim3(32, 8), 256, 0, stream>>>(ctxb, wot, x1, wo_b, x, 4096, 1024, 1024);
  // LN2 -> xn
  ln_kernel<<<4096, 256, 0, stream>>>(x1, ln2g, ln2b, xn);
  // FFN1 + b1 + GELU -> h (bf16)
  gemm_bt<1><<<dim3(32, 32), 256, 0, stream>>>(xn, w1t, hbuf, b1, nullptr, 4096, 4096, 1024);
  // FFN2 + b2 + residual x1 -> d_out (f32)
  gemm_bt<2><<<dim3(32, 8), 256, 0, stream>>>(hbuf, w2t, (float*)d_out, b2, x1, 4096, 1024, 4096);

  (void)in_sizes; (void)n_in; (void)out_size; (void)ws_size;
}